// Round 5
// baseline (326.302 us; speedup 1.0000x reference)
//
#include <hip/hip_runtime.h>
#include <hip/hip_fp16.h>
#include <math.h>

#define N_NODE 50000
#define D_FEAT 128
#define N_EDGE 625000
#define SIM_THRESH 0.1f
// screen = fp16-row x fp8-col: dot-error std ~2.4e-3; 0.03 margin is ~12 sigma
#define SCREEN_LO 0.07f
// fp16 sim error std ~3.5e-5; 5e-4 band is ~14x margin
#define BAND_EPS 5e-4f
#define MAXDEG 128   // LDS sim buffer per row; P(Poisson(12.5) > 128) ~ 0

typedef float v2f __attribute__((ext_vector_type(2)));

// ===========================================================================
// FAST PATH (CSR row-sorted, node-centric)
// ===========================================================================

// K1: per-node inv-norm + fp16/fp8 normalized tables, fused with per-edge
// row-degree counting. bcnt must be zeroed before this kernel (memset).
__global__ void prep_count_kernel(const float* __restrict__ feat,
                                  const int* __restrict__ row,
                                  float* __restrict__ inv_nrm,
                                  __half* __restrict__ fn16,
                                  unsigned int* __restrict__ fp8tab,
                                  unsigned int* __restrict__ bcnt) {
    int g = blockIdx.x * blockDim.x + threadIdx.x;
    if (g < N_EDGE) atomicAdd(&bcnt[row[g]], 1u);
    int node = g >> 5;
    int lane = g & 31;
    if (node >= N_NODE) return;
    float4 v = ((const float4*)(feat + (size_t)node * D_FEAT))[lane];
    float ss = v.x * v.x + v.y * v.y + v.z * v.z + v.w * v.w;
#pragma unroll
    for (int o = 16; o > 0; o >>= 1) ss += __shfl_down(ss, o, 32);
    ss = __shfl(ss, 0, 32);
    float inv = 1.0f / fmaxf(sqrtf(ss), 1e-12f);
    if (lane == 0) inv_nrm[node] = inv;
    float x0 = v.x * inv, x1 = v.y * inv, x2 = v.z * inv, x3 = v.w * inv;
    __half2 h0 = __floats2half2_rn(x0, x1);
    __half2 h1 = __floats2half2_rn(x2, x3);
    uint2 p;
    p.x = *(unsigned int*)&h0;
    p.y = *(unsigned int*)&h1;
    ((uint2*)(fn16 + (size_t)node * D_FEAT))[lane] = p;
    int w = __builtin_amdgcn_cvt_pk_fp8_f32(x0, x1, 0, false);
    w = __builtin_amdgcn_cvt_pk_fp8_f32(x2, x3, w, true);
    fp8tab[(size_t)node * 32 + lane] = (unsigned int)w;
}

// K2: single-workgroup exclusive scan of 50k bin counts -> bstart[N+1],
// plus a mutable cursor copy for the scatter.
__global__ __launch_bounds__(1024)
void scan_kernel(const unsigned int* __restrict__ cnt,
                 unsigned int* __restrict__ bstart,   // [N_NODE+1]
                 unsigned int* __restrict__ cursor) { // [N_NODE]
    __shared__ unsigned int ls[1024];
    const int CH = (N_NODE + 1023) / 1024;  // 49
    int t = threadIdx.x;
    int base = t * CH;
    unsigned int s = 0;
    for (int i = 0; i < CH; i++) {
        int idx = base + i;
        if (idx < N_NODE) s += cnt[idx];
    }
    ls[t] = s;
    __syncthreads();
    for (int off = 1; off < 1024; off <<= 1) {
        unsigned int v = (t >= off) ? ls[t - off] : 0u;
        __syncthreads();
        ls[t] += v;
        __syncthreads();
    }
    unsigned int run = (t == 0) ? 0u : ls[t - 1];
    for (int i = 0; i < CH; i++) {
        int idx = base + i;
        if (idx <= N_NODE) {
            bstart[idx] = run;
            if (idx < N_NODE) { cursor[idx] = run; run += cnt[idx]; }
        }
    }
}

// K3: scatter edges into CSR order as (col, orig_idx) pairs.
__global__ void scatter_kernel(const int* __restrict__ row,
                               const int* __restrict__ col,
                               unsigned int* __restrict__ cursor,
                               uint2* __restrict__ pairs) {
    int e = blockIdx.x * blockDim.x + threadIdx.x;
    if (e >= N_EDGE) return;
    int r = row[e];
    unsigned int pos = atomicAdd(&cursor[r], 1u);
    uint2 pr;
    pr.x = (unsigned int)col[e];
    pr.y = (unsigned int)e;
    pairs[pos] = pr;
}

// K4: one 16-lane group per row. Pass 1: screen (fp16row x fp8col), value
// (fp16 x fp16), exact fp32 fixup near threshold; row_sum/degree in regs;
// sims to LDS. Pass 2 (row_sum now final): full epilogue, out[orig] write.
__global__ __launch_bounds__(256)
void row_sim_kernel(const uint2* __restrict__ pairs,
                    const unsigned int* __restrict__ bstart,
                    const float* __restrict__ feat,
                    const float* __restrict__ inv_nrm,
                    const __half* __restrict__ fn16,
                    const unsigned int* __restrict__ fp8tab,
                    const float* __restrict__ ew,
                    const float* __restrict__ gate,
                    float* __restrict__ simspill,
                    float* __restrict__ out) {
    __shared__ float simbuf[16][MAXDEG];
    int g = blockIdx.x * 16 + (threadIdx.x >> 4);
    int lane = threadIdx.x & 15;
    int lg = threadIdx.x >> 4;
    if (g >= N_NODE) return;
    unsigned int s0 = bstart[g], s1 = bstart[g + 1];
    if (s0 == s1) return;

    // row fragment (fp16 table) as 8 fp32 values per lane
    float4 a = ((const float4*)(fn16 + (size_t)g * D_FEAT))[lane];
    const __half2* ah = (const __half2*)&a;
    float2 af[4];
#pragma unroll
    for (int i = 0; i < 4; i++) af[i] = __half22float2(ah[i]);

    float row_sum = 0.0f, deg = 0.0f;

    for (unsigned int p = s0; p < s1; p++) {
        uint2 pr = pairs[p];                 // uniform addr -> broadcast load
        int c = (int)pr.x;
        // tier 1: fp8 col screen
        uint2 bw = ((const uint2*)(fp8tab + (size_t)c * 32))[lane];
        v2f b01 = __builtin_amdgcn_cvt_pk_f32_fp8((int)bw.x, false);
        v2f b23 = __builtin_amdgcn_cvt_pk_f32_fp8((int)bw.x, true);
        v2f b45 = __builtin_amdgcn_cvt_pk_f32_fp8((int)bw.y, false);
        v2f b67 = __builtin_amdgcn_cvt_pk_f32_fp8((int)bw.y, true);
        float d = 0.0f;
        d = fmaf(af[0].x, b01.x, d); d = fmaf(af[0].y, b01.y, d);
        d = fmaf(af[1].x, b23.x, d); d = fmaf(af[1].y, b23.y, d);
        d = fmaf(af[2].x, b45.x, d); d = fmaf(af[2].y, b45.y, d);
        d = fmaf(af[3].x, b67.x, d); d = fmaf(af[3].y, b67.y, d);
#pragma unroll
        for (int o = 8; o > 0; o >>= 1) d += __shfl_down(d, o, 16);
        d = __shfl(d, 0, 16);

        float s = 0.0f;
        if (d > SCREEN_LO) {
            // tier 2: fp16 value
            float4 b = ((const float4*)(fn16 + (size_t)c * D_FEAT))[lane];
            const __half2* bh = (const __half2*)&b;
            float dh = 0.0f;
#pragma unroll
            for (int i = 0; i < 4; i++) {
                float2 bf = __half22float2(bh[i]);
                dh = fmaf(af[i].x, bf.x, dh);
                dh = fmaf(af[i].y, bf.y, dh);
            }
#pragma unroll
            for (int o = 8; o > 0; o >>= 1) dh += __shfl_down(dh, o, 16);
            dh = __shfl(dh, 0, 16);
            if (fabsf(dh - SIM_THRESH) < BAND_EPS) {
                // tier 3: exact fp32 (rare ~0.25%)
                const float4* fr = (const float4*)(feat + (size_t)g * D_FEAT);
                const float4* fc = (const float4*)(feat + (size_t)c * D_FEAT);
                float4 a0 = fr[lane], a1 = fr[lane + 16];
                float4 b0 = fc[lane], b1 = fc[lane + 16];
                float dd = a0.x * b0.x + a0.y * b0.y + a0.z * b0.z + a0.w * b0.w
                         + a1.x * b1.x + a1.y * b1.y + a1.z * b1.z + a1.w * b1.w;
#pragma unroll
                for (int o = 8; o > 0; o >>= 1) dd += __shfl_down(dd, o, 16);
                dd = __shfl(dd, 0, 16);
                dh = dd * inv_nrm[g] * inv_nrm[c];
            }
            s = (dh < SIM_THRESH) ? 0.0f : dh;
        }
        row_sum += s;
        deg += (s != 0.0f) ? 1.0f : 0.0f;
        unsigned int k = p - s0;
        if (lane == 0) {
            if (k < MAXDEG) simbuf[lg][k] = s;
            else simspill[p] = s;            // statistically unreachable
        }
    }

    float denom = (row_sum > 0.0f) ? row_sum : 1.0f;
    float lam = 1.0f / (deg + 1.0f);
    float gv = gate[0];

    // pass 2: lanes parallel over this row's edges (same wave -> LDS is
    // ordered without a barrier)
    for (unsigned int p = s0 + lane; p < s1; p += 16) {
        uint2 pr = pairs[p];
        int c = (int)pr.x;
        unsigned int orig = pr.y;
        unsigned int k = p - s0;
        float s = (k < MAXDEG) ? simbuf[lg][k] : simspill[p];
        float att = s / denom;
        if (c == g) att += lam;
        att = expf(att);
        float o = gv * ew[orig] + (1.0f - gv) * att;
        out[orig] = fmaxf(o, 0.0f);
    }
}

// ===========================================================================
// FALLBACK (R4 proven path) if ws is too small for the CSR arrays.
// ===========================================================================
__global__ void prep_kernel(const float* __restrict__ feat,
                            float* __restrict__ inv_nrm,
                            __half* __restrict__ fn16,
                            unsigned int* __restrict__ fp8tab,
                            float* __restrict__ row_sum,
                            float* __restrict__ degree) {
    int g = blockIdx.x * blockDim.x + threadIdx.x;
    if (g < N_NODE) { row_sum[g] = 0.0f; degree[g] = 0.0f; }
    int node = g >> 5;
    int lane = g & 31;
    if (node >= N_NODE) return;
    float4 v = ((const float4*)(feat + (size_t)node * D_FEAT))[lane];
    float ss = v.x * v.x + v.y * v.y + v.z * v.z + v.w * v.w;
#pragma unroll
    for (int o = 16; o > 0; o >>= 1) ss += __shfl_down(ss, o, 32);
    ss = __shfl(ss, 0, 32);
    float inv = 1.0f / fmaxf(sqrtf(ss), 1e-12f);
    if (lane == 0) inv_nrm[node] = inv;
    float x0 = v.x * inv, x1 = v.y * inv, x2 = v.z * inv, x3 = v.w * inv;
    __half2 h0 = __floats2half2_rn(x0, x1);
    __half2 h1 = __floats2half2_rn(x2, x3);
    uint2 p;
    p.x = *(unsigned int*)&h0;
    p.y = *(unsigned int*)&h1;
    ((uint2*)(fn16 + (size_t)node * D_FEAT))[lane] = p;
    int w = __builtin_amdgcn_cvt_pk_fp8_f32(x0, x1, 0, false);
    w = __builtin_amdgcn_cvt_pk_fp8_f32(x2, x3, w, true);
    fp8tab[(size_t)node * 32 + lane] = (unsigned int)w;
}

__global__ void edge_sim8_kernel(const int* __restrict__ row,
                                 const int* __restrict__ col,
                                 const float* __restrict__ feat,
                                 const float* __restrict__ inv_nrm,
                                 const __half* __restrict__ fn16,
                                 const unsigned int* __restrict__ fp8tab,
                                 float* __restrict__ sim_out,
                                 float* __restrict__ row_sum,
                                 float* __restrict__ degree) {
    int g = blockIdx.x * blockDim.x + threadIdx.x;
    int edge = g >> 4;
    int lane = g & 15;
    if (edge >= N_EDGE) return;
    int r = row[edge];
    int c = col[edge];
    uint2 aw = ((const uint2*)(fp8tab + (size_t)r * 32))[lane];
    uint2 bw = ((const uint2*)(fp8tab + (size_t)c * 32))[lane];
    v2f a01 = __builtin_amdgcn_cvt_pk_f32_fp8((int)aw.x, false);
    v2f a23 = __builtin_amdgcn_cvt_pk_f32_fp8((int)aw.x, true);
    v2f a45 = __builtin_amdgcn_cvt_pk_f32_fp8((int)aw.y, false);
    v2f a67 = __builtin_amdgcn_cvt_pk_f32_fp8((int)aw.y, true);
    v2f b01 = __builtin_amdgcn_cvt_pk_f32_fp8((int)bw.x, false);
    v2f b23 = __builtin_amdgcn_cvt_pk_f32_fp8((int)bw.x, true);
    v2f b45 = __builtin_amdgcn_cvt_pk_f32_fp8((int)bw.y, false);
    v2f b67 = __builtin_amdgcn_cvt_pk_f32_fp8((int)bw.y, true);
    float d = 0.0f;
    d = fmaf(a01.x, b01.x, d); d = fmaf(a01.y, b01.y, d);
    d = fmaf(a23.x, b23.x, d); d = fmaf(a23.y, b23.y, d);
    d = fmaf(a45.x, b45.x, d); d = fmaf(a45.y, b45.y, d);
    d = fmaf(a67.x, b67.x, d); d = fmaf(a67.y, b67.y, d);
#pragma unroll
    for (int o = 8; o > 0; o >>= 1) d += __shfl_down(d, o, 16);
    d = __shfl(d, 0, 16);
    float s = 0.0f;
    if (d > SCREEN_LO) {
        float4 a = ((const float4*)(fn16 + (size_t)r * D_FEAT))[lane];
        float4 b = ((const float4*)(fn16 + (size_t)c * D_FEAT))[lane];
        const __half2* ah = (const __half2*)&a;
        const __half2* bh = (const __half2*)&b;
        float dh = 0.0f;
#pragma unroll
        for (int i = 0; i < 4; i++) {
            float2 afv = __half22float2(ah[i]);
            float2 bfv = __half22float2(bh[i]);
            dh = fmaf(afv.x, bfv.x, dh);
            dh = fmaf(afv.y, bfv.y, dh);
        }
#pragma unroll
        for (int o = 8; o > 0; o >>= 1) dh += __shfl_down(dh, o, 16);
        dh = __shfl(dh, 0, 16);
        if (fabsf(dh - SIM_THRESH) < BAND_EPS) {
            const float4* fr = (const float4*)(feat + (size_t)r * D_FEAT);
            const float4* fc = (const float4*)(feat + (size_t)c * D_FEAT);
            float4 a0 = fr[lane], a1 = fr[lane + 16];
            float4 b0 = fc[lane], b1 = fc[lane + 16];
            float dd = a0.x * b0.x + a0.y * b0.y + a0.z * b0.z + a0.w * b0.w
                     + a1.x * b1.x + a1.y * b1.y + a1.z * b1.z + a1.w * b1.w;
#pragma unroll
            for (int o = 8; o > 0; o >>= 1) dd += __shfl_down(dd, o, 16);
            dd = __shfl(dd, 0, 16);
            dh = dd * inv_nrm[r] * inv_nrm[c];
        }
        s = (dh < SIM_THRESH) ? 0.0f : dh;
    }
    if (lane == 0) {
        sim_out[edge] = s;
        if (s != 0.0f) {
            atomicAdd(&row_sum[r], s);
            atomicAdd(&degree[r], 1.0f);
        }
    }
}

__global__ void edge_out_kernel(const int* __restrict__ row,
                                const int* __restrict__ col,
                                const float* __restrict__ sim,
                                const float* __restrict__ row_sum,
                                const float* __restrict__ degree,
                                const float* __restrict__ ew,
                                const float* __restrict__ gate,
                                float* __restrict__ out) {
    int e = blockIdx.x * blockDim.x + threadIdx.x;
    if (e >= N_EDGE) return;
    int r = row[e];
    float rs = row_sum[r];
    float denom = (rs > 0.0f) ? rs : 1.0f;
    float att = sim[e] / denom;
    if (r == col[e]) att += 1.0f / (degree[r] + 1.0f);
    att = expf(att);
    float gv = gate[0];
    float o = gv * ew[e] + (1.0f - gv) * att;
    out[e] = fmaxf(o, 0.0f);
}

// ===========================================================================
// Launch
// ===========================================================================
extern "C" void kernel_launch(void* const* d_in, const int* in_sizes, int n_in,
                              void* d_out, int out_size, void* d_ws, size_t ws_size,
                              hipStream_t stream) {
    const int*   edge_index = (const int*)d_in[0];   // [2, E]: row then col
    const float* ew         = (const float*)d_in[1];
    const float* feat       = (const float*)d_in[2];
    const float* gate       = (const float*)d_in[3];
    float*       out        = (float*)d_out;

    const int* row = edge_index;
    const int* col = edge_index + N_EDGE;

    const int block = 256;

    // ---- fast-path ws layout ----
    char* base = (char*)d_ws;
    size_t off = 0;
    uint2* pairs = (uint2*)(base + off);           off += (size_t)N_EDGE * 8;
    __half* fn16 = (__half*)(base + off);          off += (size_t)N_NODE * D_FEAT * 2;
    unsigned int* fp8tab = (unsigned int*)(base + off); off += (size_t)N_NODE * D_FEAT;
    float* inv_nrm = (float*)(base + off);         off += (size_t)N_NODE * 4;
    unsigned int* bstart = (unsigned int*)(base + off); off += (size_t)(N_NODE + 1) * 4;
    unsigned int* cursor = (unsigned int*)(base + off); off += (size_t)N_NODE * 4;
    unsigned int* bcnt = (unsigned int*)(base + off);   off += (size_t)N_NODE * 4;
    float* simspill = (float*)(base + off);        off += (size_t)N_EDGE * 4;
    size_t need_fast = off;

    if (ws_size >= need_fast) {
        hipMemsetAsync(bcnt, 0, (size_t)N_NODE * 4, stream);
        {
            long long threads = (long long)N_NODE * 32;   // >= N_EDGE too
            prep_count_kernel<<<(int)((threads + block - 1) / block), block, 0, stream>>>(
                feat, row, inv_nrm, fn16, fp8tab, bcnt);
        }
        scan_kernel<<<1, 1024, 0, stream>>>(bcnt, bstart, cursor);
        scatter_kernel<<<(N_EDGE + block - 1) / block, block, 0, stream>>>(
            row, col, cursor, pairs);
        {
            int blocks = (N_NODE + 15) / 16;              // 16 rows per block
            row_sim_kernel<<<blocks, block, 0, stream>>>(
                pairs, bstart, feat, inv_nrm, fn16, fp8tab, ew, gate,
                simspill, out);
        }
        return;
    }

    // ---- fallback: R4 layout & kernels ----
    float* row_sum = (float*)d_ws;
    float* degree  = row_sum + N_NODE;
    float* inv_nrm2 = degree + N_NODE;
    float* sim     = inv_nrm2 + N_NODE;
    __half* fn16b  = (__half*)(sim + N_EDGE);
    unsigned int* fp8tabb = (unsigned int*)(fn16b + (size_t)N_NODE * D_FEAT);
    {
        long long threads = (long long)N_NODE * 32;
        prep_kernel<<<(int)((threads + block - 1) / block), block, 0, stream>>>(
            feat, inv_nrm2, fn16b, fp8tabb, row_sum, degree);
    }
    {
        long long threads = (long long)N_EDGE * 16;
        edge_sim8_kernel<<<(int)((threads + block - 1) / block), block, 0, stream>>>(
            row, col, feat, inv_nrm2, fn16b, fp8tabb, sim, row_sum, degree);
    }
    edge_out_kernel<<<(N_EDGE + block - 1) / block, block, 0, stream>>>(
        row, col, sim, row_sum, degree, ew, gate, out);
}

// Round 6
// 237.902 us; speedup vs baseline: 1.3716x; 1.3716x over previous
//
#include <hip/hip_runtime.h>
#include <hip/hip_fp16.h>
#include <math.h>

#define N_NODE 50000
#define D_FEAT 128
#define N_EDGE 625000
#define SIM_THRESH 0.1f
// fp8 screen: dot-error std ~3.4e-3, margin 0.03 is ~9 sigma.
#define SCREEN_LO 0.07f
// fp16 sim error std ~3.5e-5; 5e-4 band is ~14x margin.
#define BAND_EPS 5e-4f

// 8 col slices of 6250 nodes: per-XCD col working set = 0.8MB fp8 + ~1.6MB
// hot fp16 < 4MiB L2. blockIdx%8 ~ XCD (round-robin heuristic; perf-only).
#define N_SLICE 8
#define SLICE_DIV 6250

typedef float v2f __attribute__((ext_vector_type(2)));

// ===========================================================================
// K1: per-node inv-norm; normalized fp16 value table + fp8 e4m3 screen table;
// zero row_sum/degree (ws poisoned 0xAA). 32 lanes/node.
// ===========================================================================
__global__ void prep_kernel(const float* __restrict__ feat,
                            float* __restrict__ inv_nrm,
                            __half* __restrict__ fn16,
                            unsigned int* __restrict__ fp8tab,
                            float* __restrict__ row_sum,
                            float* __restrict__ degree) {
    int g = blockIdx.x * blockDim.x + threadIdx.x;
    if (g < N_NODE) { row_sum[g] = 0.0f; degree[g] = 0.0f; }
    int node = g >> 5;
    int lane = g & 31;
    if (node >= N_NODE) return;
    float4 v = ((const float4*)(feat + (size_t)node * D_FEAT))[lane];
    float ss = v.x * v.x + v.y * v.y + v.z * v.z + v.w * v.w;
#pragma unroll
    for (int o = 16; o > 0; o >>= 1) ss += __shfl_down(ss, o, 32);
    ss = __shfl(ss, 0, 32);
    float inv = 1.0f / fmaxf(sqrtf(ss), 1e-12f);
    if (lane == 0) inv_nrm[node] = inv;
    float x0 = v.x * inv, x1 = v.y * inv, x2 = v.z * inv, x3 = v.w * inv;
    __half2 h0 = __floats2half2_rn(x0, x1);
    __half2 h1 = __floats2half2_rn(x2, x3);
    uint2 p;
    p.x = *(unsigned int*)&h0;
    p.y = *(unsigned int*)&h1;
    ((uint2*)(fn16 + (size_t)node * D_FEAT))[lane] = p;
    int w = __builtin_amdgcn_cvt_pk_fp8_f32(x0, x1, 0, false);
    w = __builtin_amdgcn_cvt_pk_fp8_f32(x2, x3, w, true);
    fp8tab[(size_t)node * 32 + lane] = (unsigned int)w;
}

// ===========================================================================
// K2: per-edge sim, XCD col-sliced. Block b owns col slice (b&7); chunk index
// (b>>3) covers 64 edges. Each 16-lane group examines one edge and processes
// it only if its col falls in the block's slice. Three-tier precision as R4:
//   fp8 screen -> fp16 value (>0.07, ~21%) -> fp32 exact (band, ~0.25%)
// ===========================================================================
__global__ __launch_bounds__(256)
void edge_sim8_sliced_kernel(const int* __restrict__ row,
                             const int* __restrict__ col,
                             const float* __restrict__ feat,
                             const float* __restrict__ inv_nrm,
                             const __half* __restrict__ fn16,
                             const unsigned int* __restrict__ fp8tab,
                             float* __restrict__ sim_out,
                             float* __restrict__ row_sum,
                             float* __restrict__ degree) {
    int slice = blockIdx.x & (N_SLICE - 1);
    int chunk = blockIdx.x >> 3;          // 64 edges per chunk
    int grp  = threadIdx.x >> 4;
    int lane = threadIdx.x & 15;

#pragma unroll
    for (int n = 0; n < 4; n++) {
        int e = chunk * 64 + n * 16 + grp;
        if (e >= N_EDGE) break;
        int c = col[e];                    // broadcast (all lanes same addr)
        if ((unsigned)c / SLICE_DIV != (unsigned)slice) continue;
        int r = row[e];

        // --- tier 1: fp8 screen ---
        uint2 aw = ((const uint2*)(fp8tab + (size_t)r * 32))[lane];
        uint2 bw = ((const uint2*)(fp8tab + (size_t)c * 32))[lane];
        v2f a01 = __builtin_amdgcn_cvt_pk_f32_fp8((int)aw.x, false);
        v2f a23 = __builtin_amdgcn_cvt_pk_f32_fp8((int)aw.x, true);
        v2f a45 = __builtin_amdgcn_cvt_pk_f32_fp8((int)aw.y, false);
        v2f a67 = __builtin_amdgcn_cvt_pk_f32_fp8((int)aw.y, true);
        v2f b01 = __builtin_amdgcn_cvt_pk_f32_fp8((int)bw.x, false);
        v2f b23 = __builtin_amdgcn_cvt_pk_f32_fp8((int)bw.x, true);
        v2f b45 = __builtin_amdgcn_cvt_pk_f32_fp8((int)bw.y, false);
        v2f b67 = __builtin_amdgcn_cvt_pk_f32_fp8((int)bw.y, true);
        float d = 0.0f;
        d = fmaf(a01.x, b01.x, d); d = fmaf(a01.y, b01.y, d);
        d = fmaf(a23.x, b23.x, d); d = fmaf(a23.y, b23.y, d);
        d = fmaf(a45.x, b45.x, d); d = fmaf(a45.y, b45.y, d);
        d = fmaf(a67.x, b67.x, d); d = fmaf(a67.y, b67.y, d);
#pragma unroll
        for (int o = 8; o > 0; o >>= 1) d += __shfl_down(d, o, 16);
        d = __shfl(d, 0, 16);

        float s = 0.0f;
        if (d > SCREEN_LO) {
            // --- tier 2: fp16 value ---
            float4 a = ((const float4*)(fn16 + (size_t)r * D_FEAT))[lane];
            float4 b = ((const float4*)(fn16 + (size_t)c * D_FEAT))[lane];
            const __half2* ah = (const __half2*)&a;
            const __half2* bh = (const __half2*)&b;
            float dh = 0.0f;
#pragma unroll
            for (int i = 0; i < 4; i++) {
                float2 afv = __half22float2(ah[i]);
                float2 bfv = __half22float2(bh[i]);
                dh = fmaf(afv.x, bfv.x, dh);
                dh = fmaf(afv.y, bfv.y, dh);
            }
#pragma unroll
            for (int o = 8; o > 0; o >>= 1) dh += __shfl_down(dh, o, 16);
            dh = __shfl(dh, 0, 16);
            if (fabsf(dh - SIM_THRESH) < BAND_EPS) {
                // --- tier 3: exact fp32 (rare) ---
                const float4* fr = (const float4*)(feat + (size_t)r * D_FEAT);
                const float4* fc = (const float4*)(feat + (size_t)c * D_FEAT);
                float4 a0 = fr[lane], a1 = fr[lane + 16];
                float4 b0 = fc[lane], b1 = fc[lane + 16];
                float dd = a0.x * b0.x + a0.y * b0.y + a0.z * b0.z + a0.w * b0.w
                         + a1.x * b1.x + a1.y * b1.y + a1.z * b1.z + a1.w * b1.w;
#pragma unroll
                for (int o = 8; o > 0; o >>= 1) dd += __shfl_down(dd, o, 16);
                dd = __shfl(dd, 0, 16);
                dh = dd * inv_nrm[r] * inv_nrm[c];
            }
            s = (dh < SIM_THRESH) ? 0.0f : dh;
        }
        if (lane == 0) {
            sim_out[e] = s;
            if (s != 0.0f) {
                atomicAdd(&row_sum[r], s);
                atomicAdd(&degree[r], 1.0f);
            }
        }
    }
}

// ===========================================================================
// K3: epilogue — normalize, diagonal lam, exp, gate blend, clamp.
// ===========================================================================
__global__ void edge_out_kernel(const int* __restrict__ row,
                                const int* __restrict__ col,
                                const float* __restrict__ sim,
                                const float* __restrict__ row_sum,
                                const float* __restrict__ degree,
                                const float* __restrict__ ew,
                                const float* __restrict__ gate,
                                float* __restrict__ out) {
    int e = blockIdx.x * blockDim.x + threadIdx.x;
    if (e >= N_EDGE) return;
    int r = row[e];
    float rs = row_sum[r];
    float denom = (rs > 0.0f) ? rs : 1.0f;
    float att = sim[e] / denom;
    if (r == col[e]) att += 1.0f / (degree[r] + 1.0f);
    att = expf(att);
    float gv = gate[0];
    float o = gv * ew[e] + (1.0f - gv) * att;
    out[e] = fmaxf(o, 0.0f);
}

// ===========================================================================
// Fallback (pure fp32) if ws too small.
// ===========================================================================
__global__ void inv_norm_kernel(const float* __restrict__ feat,
                                float* __restrict__ inv_nrm,
                                float* __restrict__ row_sum,
                                float* __restrict__ degree) {
    int g = blockIdx.x * blockDim.x + threadIdx.x;
    if (g < N_NODE) { row_sum[g] = 0.0f; degree[g] = 0.0f; }
    int node = g >> 5;
    int lane = g & 31;
    if (node >= N_NODE) return;
    float4 v = ((const float4*)(feat + (size_t)node * D_FEAT))[lane];
    float ss = v.x * v.x + v.y * v.y + v.z * v.z + v.w * v.w;
#pragma unroll
    for (int o = 16; o > 0; o >>= 1) ss += __shfl_down(ss, o, 32);
    if (lane == 0) inv_nrm[node] = 1.0f / fmaxf(sqrtf(ss), 1e-12f);
}

__global__ void edge_sim_kernel(const int* __restrict__ row,
                                const int* __restrict__ col,
                                const float* __restrict__ feat,
                                const float* __restrict__ inv_nrm,
                                float* __restrict__ sim_out,
                                float* __restrict__ row_sum,
                                float* __restrict__ degree) {
    int g = blockIdx.x * blockDim.x + threadIdx.x;
    int edge = g >> 5;
    int lane = g & 31;
    if (edge >= N_EDGE) return;
    int r = row[edge];
    int c = col[edge];
    float4 a = ((const float4*)(feat + (size_t)r * D_FEAT))[lane];
    float4 b = ((const float4*)(feat + (size_t)c * D_FEAT))[lane];
    float d = a.x * b.x + a.y * b.y + a.z * b.z + a.w * b.w;
#pragma unroll
    for (int o = 16; o > 0; o >>= 1) d += __shfl_down(d, o, 32);
    if (lane == 0) {
        float s = d * inv_nrm[r] * inv_nrm[c];
        if (s < SIM_THRESH) s = 0.0f;
        sim_out[edge] = s;
        if (s != 0.0f) {
            atomicAdd(&row_sum[r], s);
            atomicAdd(&degree[r], 1.0f);
        }
    }
}

// ===========================================================================
// Launch — 3 dispatches (grid.sync costs ~600us on MI355X: never fuse across
// the reduction barrier; CSR sort costs more than it saves: see R5).
// ===========================================================================
extern "C" void kernel_launch(void* const* d_in, const int* in_sizes, int n_in,
                              void* d_out, int out_size, void* d_ws, size_t ws_size,
                              hipStream_t stream) {
    const int*   edge_index = (const int*)d_in[0];   // [2, E]: row then col
    const float* ew         = (const float*)d_in[1];
    const float* feat       = (const float*)d_in[2];
    const float* gate       = (const float*)d_in[3];
    float*       out        = (float*)d_out;

    const int* row = edge_index;
    const int* col = edge_index + N_EDGE;

    // ws layout: row_sum[N] | degree[N] | inv_nrm[N] | sim[E]
    //            | fn16[N*128 halves] | fp8tab[N*32 uints]
    float* row_sum = (float*)d_ws;
    float* degree  = row_sum + N_NODE;
    float* inv_nrm = degree + N_NODE;
    float* sim     = inv_nrm + N_NODE;
    __half* fn16   = (__half*)(sim + N_EDGE);
    unsigned int* fp8tab = (unsigned int*)(fn16 + (size_t)N_NODE * D_FEAT);

    size_t need = (size_t)(3 * N_NODE + N_EDGE) * 4
                + (size_t)N_NODE * D_FEAT * 2
                + (size_t)N_NODE * D_FEAT;

    const int block = 256;

    if (ws_size >= need) {
        {
            long long threads = (long long)N_NODE * 32;
            prep_kernel<<<(int)((threads + block - 1) / block), block, 0, stream>>>(
                feat, inv_nrm, fn16, fp8tab, row_sum, degree);
        }
        {
            // 64 edges per chunk; 8 slice-classes of blocks per chunk.
            int chunks = (N_EDGE + 63) / 64;             // 9766
            int blocks = chunks * N_SLICE;               // 78128
            edge_sim8_sliced_kernel<<<blocks, block, 0, stream>>>(
                row, col, feat, inv_nrm, fn16, fp8tab, sim, row_sum, degree);
        }
        edge_out_kernel<<<(N_EDGE + block - 1) / block, block, 0, stream>>>(
            row, col, sim, row_sum, degree, ew, gate, out);
    } else {
        {
            long long threads = (long long)N_NODE * 32;
            inv_norm_kernel<<<(int)((threads + block - 1) / block), block, 0, stream>>>(
                feat, inv_nrm, row_sum, degree);
        }
        {
            long long threads = (long long)N_EDGE * 32;
            edge_sim_kernel<<<(int)((threads + block - 1) / block), block, 0, stream>>>(
                row, col, feat, inv_nrm, sim, row_sum, degree);
        }
        edge_out_kernel<<<(N_EDGE + block - 1) / block, block, 0, stream>>>(
            row, col, sim, row_sum, degree, ew, gate, out);
    }
}

// Round 7
// 126.534 us; speedup vs baseline: 2.5788x; 1.8801x over previous
//
#include <hip/hip_runtime.h>
#include <hip/hip_fp16.h>
#include <math.h>

#define N_NODE 50000
#define D_FEAT 128
#define N_EDGE 625000
#define SIM_THRESH 0.1f
// fp8 screen: dot-error std ~3.4e-3; 0.02 margin is ~5.9 sigma.
#define SCREEN_LO 0.08f
// fp16 sim error std ~3.5e-5; 5e-4 band is ~14x margin.
#define BAND_EPS 5e-4f

typedef float v2f __attribute__((ext_vector_type(2)));

// ===========================================================================
// K1: per-node inv-norm; normalized fp16 value table + fp8 e4m3 screen table;
// zero row_sum/degree (ws poisoned 0xAA). 32 lanes/node.
// ===========================================================================
__global__ void prep_kernel(const float* __restrict__ feat,
                            float* __restrict__ inv_nrm,
                            __half* __restrict__ fn16,
                            unsigned int* __restrict__ fp8tab,
                            float* __restrict__ row_sum,
                            float* __restrict__ degree) {
    int g = blockIdx.x * blockDim.x + threadIdx.x;
    if (g < N_NODE) { row_sum[g] = 0.0f; degree[g] = 0.0f; }
    int node = g >> 5;
    int lane = g & 31;
    if (node >= N_NODE) return;
    float4 v = ((const float4*)(feat + (size_t)node * D_FEAT))[lane];
    float ss = v.x * v.x + v.y * v.y + v.z * v.z + v.w * v.w;
#pragma unroll
    for (int o = 16; o > 0; o >>= 1) ss += __shfl_down(ss, o, 32);
    ss = __shfl(ss, 0, 32);
    float inv = 1.0f / fmaxf(sqrtf(ss), 1e-12f);
    if (lane == 0) inv_nrm[node] = inv;
    float x0 = v.x * inv, x1 = v.y * inv, x2 = v.z * inv, x3 = v.w * inv;
    __half2 h0 = __floats2half2_rn(x0, x1);
    __half2 h1 = __floats2half2_rn(x2, x3);
    uint2 p;
    p.x = *(unsigned int*)&h0;
    p.y = *(unsigned int*)&h1;
    ((uint2*)(fn16 + (size_t)node * D_FEAT))[lane] = p;
    int w = __builtin_amdgcn_cvt_pk_fp8_f32(x0, x1, 0, false);
    w = __builtin_amdgcn_cvt_pk_fp8_f32(x2, x3, w, true);
    fp8tab[(size_t)node * 32 + lane] = (unsigned int)w;
}

// ===========================================================================
// K2: per-edge sim, 8 lanes/edge (8 edges per wave). Three-tier precision:
//   fp8 screen (uint4/lane)  ->  fp16 value (sim8 > 0.08, ~18%)
//                            ->  fp32 exact (|sim16-0.1| < 5e-4, ~0.25%)
// ===========================================================================
__global__ __launch_bounds__(256)
void edge_sim8_kernel(const int* __restrict__ row,
                      const int* __restrict__ col,
                      const float* __restrict__ feat,
                      const float* __restrict__ inv_nrm,
                      const __half* __restrict__ fn16,
                      const unsigned int* __restrict__ fp8tab,
                      float* __restrict__ sim_out,
                      float* __restrict__ row_sum,
                      float* __restrict__ degree) {
    int g = blockIdx.x * blockDim.x + threadIdx.x;
    int edge = g >> 3;
    int lane = g & 7;
    if (edge >= N_EDGE) return;
    int r = row[edge];
    int c = col[edge];

    // --- tier 1: fp8 screen, 16 B/lane per endpoint (one 128B line/row) ---
    uint4 aw = ((const uint4*)(fp8tab + (size_t)r * 32))[lane];
    uint4 bw = ((const uint4*)(fp8tab + (size_t)c * 32))[lane];
    float d = 0.0f;
    {
        const unsigned int* awp = (const unsigned int*)&aw;
        const unsigned int* bwp = (const unsigned int*)&bw;
#pragma unroll
        for (int i = 0; i < 4; i++) {
            v2f alo = __builtin_amdgcn_cvt_pk_f32_fp8((int)awp[i], false);
            v2f ahi = __builtin_amdgcn_cvt_pk_f32_fp8((int)awp[i], true);
            v2f blo = __builtin_amdgcn_cvt_pk_f32_fp8((int)bwp[i], false);
            v2f bhi = __builtin_amdgcn_cvt_pk_f32_fp8((int)bwp[i], true);
            d = fmaf(alo.x, blo.x, d); d = fmaf(alo.y, blo.y, d);
            d = fmaf(ahi.x, bhi.x, d); d = fmaf(ahi.y, bhi.y, d);
        }
    }
#pragma unroll
    for (int o = 4; o > 0; o >>= 1) d += __shfl_down(d, o, 8);
    d = __shfl(d, 0, 8);   // broadcast -> group-uniform branch

    float s = 0.0f;
    if (d > SCREEN_LO) {
        // --- tier 2: fp16 value, 32 B/lane per endpoint ---
        const float4* ar = (const float4*)(fn16 + (size_t)r * D_FEAT);
        const float4* br = (const float4*)(fn16 + (size_t)c * D_FEAT);
        float4 a0 = ar[lane], a1 = ar[lane + 8];
        float4 b0 = br[lane], b1 = br[lane + 8];
        const __half2* ah0 = (const __half2*)&a0;
        const __half2* bh0 = (const __half2*)&b0;
        const __half2* ah1 = (const __half2*)&a1;
        const __half2* bh1 = (const __half2*)&b1;
        float dh = 0.0f;
#pragma unroll
        for (int i = 0; i < 4; i++) {
            float2 afv = __half22float2(ah0[i]);
            float2 bfv = __half22float2(bh0[i]);
            dh = fmaf(afv.x, bfv.x, dh);
            dh = fmaf(afv.y, bfv.y, dh);
            float2 afw = __half22float2(ah1[i]);
            float2 bfw = __half22float2(bh1[i]);
            dh = fmaf(afw.x, bfw.x, dh);
            dh = fmaf(afw.y, bfw.y, dh);
        }
#pragma unroll
        for (int o = 4; o > 0; o >>= 1) dh += __shfl_down(dh, o, 8);
        dh = __shfl(dh, 0, 8);
        if (fabsf(dh - SIM_THRESH) < BAND_EPS) {
            // --- tier 3: exact fp32 (rare ~0.25%) ---
            const float4* fr = (const float4*)(feat + (size_t)r * D_FEAT);
            const float4* fc = (const float4*)(feat + (size_t)c * D_FEAT);
            float dd = 0.0f;
#pragma unroll
            for (int q = 0; q < 4; q++) {
                float4 av = fr[lane + q * 8];
                float4 bv = fc[lane + q * 8];
                dd += av.x * bv.x + av.y * bv.y + av.z * bv.z + av.w * bv.w;
            }
#pragma unroll
            for (int o = 4; o > 0; o >>= 1) dd += __shfl_down(dd, o, 8);
            dd = __shfl(dd, 0, 8);
            dh = dd * inv_nrm[r] * inv_nrm[c];
        }
        s = (dh < SIM_THRESH) ? 0.0f : dh;
    }
    if (lane == 0) {
        sim_out[edge] = s;
        if (s != 0.0f) {
            atomicAdd(&row_sum[r], s);
            atomicAdd(&degree[r], 1.0f);
        }
    }
}

// ===========================================================================
// K3: epilogue — normalize, diagonal lam, exp, gate blend, clamp.
// ===========================================================================
__global__ void edge_out_kernel(const int* __restrict__ row,
                                const int* __restrict__ col,
                                const float* __restrict__ sim,
                                const float* __restrict__ row_sum,
                                const float* __restrict__ degree,
                                const float* __restrict__ ew,
                                const float* __restrict__ gate,
                                float* __restrict__ out) {
    int e = blockIdx.x * blockDim.x + threadIdx.x;
    if (e >= N_EDGE) return;
    int r = row[e];
    float rs = row_sum[r];
    float denom = (rs > 0.0f) ? rs : 1.0f;
    float att = sim[e] / denom;
    if (r == col[e]) att += 1.0f / (degree[r] + 1.0f);
    att = expf(att);
    float gv = gate[0];
    float o = gv * ew[e] + (1.0f - gv) * att;
    out[e] = fmaxf(o, 0.0f);
}

// ===========================================================================
// Fallback (pure fp32) if ws too small.
// ===========================================================================
__global__ void inv_norm_kernel(const float* __restrict__ feat,
                                float* __restrict__ inv_nrm,
                                float* __restrict__ row_sum,
                                float* __restrict__ degree) {
    int g = blockIdx.x * blockDim.x + threadIdx.x;
    if (g < N_NODE) { row_sum[g] = 0.0f; degree[g] = 0.0f; }
    int node = g >> 5;
    int lane = g & 31;
    if (node >= N_NODE) return;
    float4 v = ((const float4*)(feat + (size_t)node * D_FEAT))[lane];
    float ss = v.x * v.x + v.y * v.y + v.z * v.z + v.w * v.w;
#pragma unroll
    for (int o = 16; o > 0; o >>= 1) ss += __shfl_down(ss, o, 32);
    if (lane == 0) inv_nrm[node] = 1.0f / fmaxf(sqrtf(ss), 1e-12f);
}

__global__ void edge_sim_kernel(const int* __restrict__ row,
                                const int* __restrict__ col,
                                const float* __restrict__ feat,
                                const float* __restrict__ inv_nrm,
                                float* __restrict__ sim_out,
                                float* __restrict__ row_sum,
                                float* __restrict__ degree) {
    int g = blockIdx.x * blockDim.x + threadIdx.x;
    int edge = g >> 5;
    int lane = g & 31;
    if (edge >= N_EDGE) return;
    int r = row[edge];
    int c = col[edge];
    float4 a = ((const float4*)(feat + (size_t)r * D_FEAT))[lane];
    float4 b = ((const float4*)(feat + (size_t)c * D_FEAT))[lane];
    float d = a.x * b.x + a.y * b.y + a.z * b.z + a.w * b.w;
#pragma unroll
    for (int o = 16; o > 0; o >>= 1) d += __shfl_down(d, o, 32);
    if (lane == 0) {
        float s = d * inv_nrm[r] * inv_nrm[c];
        if (s < SIM_THRESH) s = 0.0f;
        sim_out[edge] = s;
        if (s != 0.0f) {
            atomicAdd(&row_sum[r], s);
            atomicAdd(&degree[r], 1.0f);
        }
    }
}

// ===========================================================================
// Launch — 3 dispatches. Journal constraints baked in:
//  - grid.sync costs ~600us on MI355X (R3): never fuse across the reduction.
//  - CSR/bucket permutation passes cost more than the <=24MB dedup they can
//    win (R5, R6): keep the edge order as-given.
// ===========================================================================
extern "C" void kernel_launch(void* const* d_in, const int* in_sizes, int n_in,
                              void* d_out, int out_size, void* d_ws, size_t ws_size,
                              hipStream_t stream) {
    const int*   edge_index = (const int*)d_in[0];   // [2, E]: row then col
    const float* ew         = (const float*)d_in[1];
    const float* feat       = (const float*)d_in[2];
    const float* gate       = (const float*)d_in[3];
    float*       out        = (float*)d_out;

    const int* row = edge_index;
    const int* col = edge_index + N_EDGE;

    // ws layout: row_sum[N] | degree[N] | inv_nrm[N] | sim[E]
    //            | fn16[N*128 halves] | fp8tab[N*32 uints]
    float* row_sum = (float*)d_ws;
    float* degree  = row_sum + N_NODE;
    float* inv_nrm = degree + N_NODE;
    float* sim     = inv_nrm + N_NODE;
    __half* fn16   = (__half*)(sim + N_EDGE);
    unsigned int* fp8tab = (unsigned int*)(fn16 + (size_t)N_NODE * D_FEAT);

    size_t need = (size_t)(3 * N_NODE + N_EDGE) * 4
                + (size_t)N_NODE * D_FEAT * 2
                + (size_t)N_NODE * D_FEAT;

    const int block = 256;

    if (ws_size >= need) {
        {
            long long threads = (long long)N_NODE * 32;
            prep_kernel<<<(int)((threads + block - 1) / block), block, 0, stream>>>(
                feat, inv_nrm, fn16, fp8tab, row_sum, degree);
        }
        {
            long long threads = (long long)N_EDGE * 8;
            edge_sim8_kernel<<<(int)((threads + block - 1) / block), block, 0, stream>>>(
                row, col, feat, inv_nrm, fn16, fp8tab, sim, row_sum, degree);
        }
        edge_out_kernel<<<(N_EDGE + block - 1) / block, block, 0, stream>>>(
            row, col, sim, row_sum, degree, ew, gate, out);
    } else {
        {
            long long threads = (long long)N_NODE * 32;
            inv_norm_kernel<<<(int)((threads + block - 1) / block), block, 0, stream>>>(
                feat, inv_nrm, row_sum, degree);
        }
        {
            long long threads = (long long)N_EDGE * 32;
            edge_sim_kernel<<<(int)((threads + block - 1) / block), block, 0, stream>>>(
                row, col, feat, inv_nrm, sim, row_sum, degree);
        }
        edge_out_kernel<<<(N_EDGE + block - 1) / block, block, 0, stream>>>(
            row, col, sim, row_sum, degree, ew, gate, out);
    }
}